// Round 2
// baseline (816.600 us; speedup 1.0000x reference)
//
#include <hip/hip_runtime.h>
#include <stdint.h>

typedef __attribute__((ext_vector_type(8))) short bf16x8;
typedef __attribute__((ext_vector_type(4))) float f32x4;

__device__ __forceinline__ float bf2f(unsigned short u) {
  union { unsigned int i; float f; } x; x.i = ((unsigned int)u) << 16; return x.f;
}
__device__ __forceinline__ unsigned short f2bf(float f) {
  union { float f; unsigned int i; } x; x.f = f;
  unsigned int i = x.i;
  return (unsigned short)((i + 0x7FFFu + ((i >> 16) & 1u)) >> 16);  // RNE
}

// ---------------- CSR build (edge_index arrives as int32: "integer -> const int*") --------

__global__ void count_kernel(const int* __restrict__ ei, int E, int* __restrict__ counts) {
  int e = blockIdx.x * blockDim.x + threadIdx.x;
  if (e < E) atomicAdd(&counts[ei[E + e]], 1);
}

__global__ void scan_kernel(const int* __restrict__ counts, int* __restrict__ offsets,
                            int* __restrict__ cursor, int n, int total) {
  __shared__ int sums[1024];
  int t = threadIdx.x;
  int per = (n + 1023) >> 10;
  int lo = t * per, hi = min(n, lo + per);
  if (lo > n) lo = n;
  int s = 0;
  for (int i = lo; i < hi; ++i) s += counts[i];
  sums[t] = s;
  __syncthreads();
  for (int d = 1; d < 1024; d <<= 1) {
    int v = (t >= d) ? sums[t - d] : 0;
    __syncthreads();
    sums[t] += v;
    __syncthreads();
  }
  int p = sums[t] - s;  // exclusive prefix of this thread's chunk
  for (int i = lo; i < hi; ++i) { offsets[i] = p; cursor[i] = p; p += counts[i]; }
  if (t == 0) offsets[n] = total;
}

__global__ void fill_kernel(const int* __restrict__ ei, const float* __restrict__ pseudo,
                            int E, int* __restrict__ cursor, int* __restrict__ src_s,
                            float2* __restrict__ ps_s) {
  int e = blockIdx.x * blockDim.x + threadIdx.x;
  if (e >= E) return;
  int d = ei[E + e];
  int s = ei[e];
  int p = atomicAdd(&cursor[d], 1);
  src_s[p] = s;
  ps_s[p] = ((const float2*)pseudo)[e];
}

// -------- weight repack, TRANSPOSED: Wt[64 cols][640 k] bf16; k rows 0..575 = W.flat, 576..639 = root

__global__ void wconv_kernel(const float* __restrict__ W, const float* __restrict__ root,
                             unsigned short* __restrict__ Wt) {
  int i = blockIdx.x * blockDim.x + threadIdx.x;  // 40960 total
  if (i >= 640 * 64) return;
  int co = i / 640, r = i % 640;
  float v = (r < 576) ? W[r * 64 + co] : root[(r - 576) * 64 + co];
  Wt[i] = f2bf(v);
}

// ---------------- per-node aggregation: one wave per node, lane = channel ----------------

template <bool XBF16>
__global__ void agg_kernel(const int* __restrict__ offsets, const int* __restrict__ src_s,
                           const float2* __restrict__ ps_s, const void* __restrict__ Xv,
                           unsigned short* __restrict__ A, int node0, int nodeEnd) {
  int wid = (blockIdx.x * blockDim.x + threadIdx.x) >> 6;
  int lane = threadIdx.x & 63;
  int n = node0 + wid;
  if (n >= nodeEnd) return;
  const float* Xf = (const float*)Xv;
  const unsigned short* Xh = (const unsigned short*)Xv;
  float acc[9];
#pragma unroll
  for (int k = 0; k < 9; ++k) acc[k] = 0.f;
  int beg = offsets[n], end = offsets[n + 1];
  int s_pf = 0; float2 uv_pf = make_float2(0.f, 0.f);
  if (beg < end) { s_pf = src_s[beg]; uv_pf = ps_s[beg]; }
  for (int j = beg; j < end; ++j) {
    int s = s_pf; float2 uv = uv_pf;
    if (j + 1 < end) { s_pf = src_s[j + 1]; uv_pf = ps_s[j + 1]; }  // software prefetch
    float xv = XBF16 ? bf2f(Xh[(size_t)s * 64 + lane]) : Xf[(size_t)s * 64 + lane];
    float u = uv.x, v = uv.y;
    float b0 = 0.5f * u * u - u + 0.5f, b1 = -u * u + u + 0.5f, b2 = 0.5f * u * u;
    float c0 = 0.5f * v * v - v + 0.5f, c1 = -v * v + v + 0.5f, c2 = 0.5f * v * v;
    float t0 = b0 * xv, t1 = b1 * xv, t2 = b2 * xv;
    acc[0] += t0 * c0; acc[1] += t0 * c1; acc[2] += t0 * c2;
    acc[3] += t1 * c0; acc[4] += t1 * c1; acc[5] += t1 * c2;
    acc[6] += t2 * c0; acc[7] += t2 * c1; acc[8] += t2 * c2;
  }
  float self = XBF16 ? bf2f(Xh[(size_t)n * 64 + lane]) : Xf[(size_t)n * 64 + lane];
  size_t row = (size_t)(n - node0) * 640;
#pragma unroll
  for (int k = 0; k < 9; ++k) A[row + k * 64 + lane] = f2bf(acc[k]);
  A[row + 576 + lane] = f2bf(self);
}

// ---------------- MFMA GEMM: [M,640](bf16) @ Wt^T + bias, relu; B read direct from L1/L2 ----

template <bool OUTBF16>
__global__ __launch_bounds__(256) void gemm_kernel(const unsigned short* __restrict__ A,
                                                   const unsigned short* __restrict__ Wt,
                                                   const float* __restrict__ bias,
                                                   void* __restrict__ outv, int M, int node0) {
  int tid = threadIdx.x;
  int w = tid >> 6, lane = tid & 63;
  int rowBase = blockIdx.x * 64 + w * 16;
  int rA = rowBase + (lane & 15);
  int kg = lane >> 4;
  const bool rowOK = rA < M;
  f32x4 acc[4] = {{0.f, 0.f, 0.f, 0.f}, {0.f, 0.f, 0.f, 0.f},
                  {0.f, 0.f, 0.f, 0.f}, {0.f, 0.f, 0.f, 0.f}};
#pragma unroll
  for (int kk = 0; kk < 20; ++kk) {
    int kbase = kk * 32 + kg * 8;
    bf16x8 af = {0, 0, 0, 0, 0, 0, 0, 0};
    if (rowOK) af = *(const bf16x8*)(A + (size_t)rA * 640 + kbase);
#pragma unroll
    for (int t = 0; t < 4; ++t) {
      bf16x8 bfr = *(const bf16x8*)(Wt + (size_t)(t * 16 + (lane & 15)) * 640 + kbase);
      acc[t] = __builtin_amdgcn_mfma_f32_16x16x32_bf16(af, bfr, acc[t], 0, 0, 0);
    }
  }
  // C/D layout (m89-verified): col = lane&15, row = (lane>>4)*4 + reg
  int rowE0 = rowBase + (lane >> 4) * 4;
#pragma unroll
  for (int t = 0; t < 4; ++t) {
    int col = t * 16 + (lane & 15);
    float bv = bias[col];
#pragma unroll
    for (int r = 0; r < 4; ++r) {
      int row = rowE0 + r;
      if (row < M) {
        float val = fmaxf(acc[t][r] + bv, 0.f);
        size_t idx = (size_t)(node0 + row) * 64 + col;
        if (OUTBF16) ((unsigned short*)outv)[idx] = f2bf(val);
        else ((float*)outv)[idx] = val;
      }
    }
  }
}

// ---------------- host ----------------

extern "C" void kernel_launch(void* const* d_in, const int* in_sizes, int n_in,
                              void* d_out, int out_size, void* d_ws, size_t ws_size,
                              hipStream_t stream) {
  const float* x = (const float*)d_in[0];
  const int* ei = (const int*)d_in[1];          // int inputs arrive as int32
  const float* pseudo = (const float*)d_in[2];
  const float* W1 = (const float*)d_in[3];
  const float* root1 = (const float*)d_in[4];
  const float* b1 = (const float*)d_in[5];
  const float* W2 = (const float*)d_in[6];
  const float* root2 = (const float*)d_in[7];
  const float* b2 = (const float*)d_in[8];

  const int N = in_sizes[0] / 64;
  const int E = in_sizes[1] / 2;

  char* p = (char*)d_ws;
  auto carve = [&](size_t bytes) -> void* {
    void* r = (void*)p;
    p += (bytes + 255) & ~(size_t)255;
    return r;
  };
  int* counts = (int*)carve((size_t)N * 4);
  int* offsets = (int*)carve((size_t)(N + 1) * 4);
  int* cursor = (int*)carve((size_t)N * 4);
  int* src_s = (int*)carve((size_t)E * 4);
  float2* ps_s = (float2*)carve((size_t)E * 8);
  unsigned short* Wt1 = (unsigned short*)carve(640 * 64 * 2);
  unsigned short* Wt2 = (unsigned short*)carve(640 * 64 * 2);
  unsigned short* h = (unsigned short*)carve((size_t)N * 64 * 2);
  size_t used = (size_t)(p - (char*)d_ws);
  size_t avail = ws_size > used ? ws_size - used : 0;
  long long crMax = (long long)(avail / (640 * 2));
  int CR;
  if (crMax >= (long long)N) CR = N;
  else {
    CR = (int)crMax & ~63;
    if (CR < 64) CR = 64;  // last resort
  }
  unsigned short* Agg = (unsigned short*)p;

  hipMemsetAsync(counts, 0, (size_t)N * 4, stream);
  count_kernel<<<(E + 255) / 256, 256, 0, stream>>>(ei, E, counts);
  scan_kernel<<<1, 1024, 0, stream>>>(counts, offsets, cursor, N, E);
  fill_kernel<<<(E + 255) / 256, 256, 0, stream>>>(ei, pseudo, E, cursor, src_s, ps_s);
  wconv_kernel<<<160, 256, 0, stream>>>(W1, root1, Wt1);
  wconv_kernel<<<160, 256, 0, stream>>>(W2, root2, Wt2);

  // layer 1: X = x (fp32) -> h (bf16)
  for (int n0 = 0; n0 < N; n0 += CR) {
    int ncur = min(CR, N - n0);
    agg_kernel<false><<<(ncur + 3) / 4, 256, 0, stream>>>(offsets, src_s, ps_s, x, Agg, n0, n0 + ncur);
    gemm_kernel<true><<<(ncur + 63) / 64, 256, 0, stream>>>(Agg, Wt1, b1, (void*)h, ncur, n0);
  }
  // layer 2: X = h (bf16) -> d_out (fp32)
  for (int n0 = 0; n0 < N; n0 += CR) {
    int ncur = min(CR, N - n0);
    agg_kernel<true><<<(ncur + 3) / 4, 256, 0, stream>>>(offsets, src_s, ps_s, h, Agg, n0, n0 + ncur);
    gemm_kernel<false><<<(ncur + 63) / 64, 256, 0, stream>>>(Agg, Wt2, b2, d_out, ncur, n0);
  }
}

// Round 3
// 595.275 us; speedup vs baseline: 1.3718x; 1.3718x over previous
//
#include <hip/hip_runtime.h>
#include <stdint.h>

typedef __attribute__((ext_vector_type(8))) short bf16x8;
typedef __attribute__((ext_vector_type(4))) float f32x4;

__device__ __forceinline__ float bf2f(unsigned short u) {
  union { unsigned int i; float f; } x; x.i = ((unsigned int)u) << 16; return x.f;
}
__device__ __forceinline__ unsigned short f2bf(float f) {
  union { float f; unsigned int i; } x; x.f = f;
  unsigned int i = x.i;
  return (unsigned short)((i + 0x7FFFu + ((i >> 16) & 1u)) >> 16);  // RNE
}

// ---------------- CSR build ----------------

__global__ void count_kernel(const int* __restrict__ ei, int E, int* __restrict__ counts) {
  int e = blockIdx.x * blockDim.x + threadIdx.x;
  if (e < E) atomicAdd(&counts[ei[E + e]], 1);
}

// phase 1: per-block (256 counts) sums
__global__ void scan1_kernel(const int* __restrict__ counts, int n, int* __restrict__ bsum) {
  int i = blockIdx.x * 256 + threadIdx.x;
  int v = (i < n) ? counts[i] : 0;
  int lane = threadIdx.x & 63, w = threadIdx.x >> 6;
  for (int d = 32; d > 0; d >>= 1) v += __shfl_down(v, d, 64);
  __shared__ int ws[4];
  if (lane == 0) ws[w] = v;
  __syncthreads();
  if (threadIdx.x == 0) bsum[blockIdx.x] = ws[0] + ws[1] + ws[2] + ws[3];
}

// phase 2: exclusive scan of bsum[G] in one block (512 threads, chunked, wave-scan based)
__global__ void scan2_kernel(int* __restrict__ bsum, int G) {
  int t = threadIdx.x;
  int c = (G + 511) >> 9;
  int lo = min(t * c, G), hi = min(lo + c, G);
  int s = 0;
  for (int i = lo; i < hi; ++i) s += bsum[i];
  int lane = t & 63, w = t >> 6;
  int incl = s;
  for (int d = 1; d < 64; d <<= 1) { int u = __shfl_up(incl, d, 64); if (lane >= d) incl += u; }
  __shared__ int wsum[8];
  if (lane == 63) wsum[w] = incl;
  __syncthreads();
  int wpre = 0;
  for (int i = 0; i < w; ++i) wpre += wsum[i];
  int excl = wpre + incl - s;
  for (int i = lo; i < hi; ++i) { int v = bsum[i]; bsum[i] = excl; excl += v; }
}

// phase 3: in-block exclusive scan + block prefix -> offsets, cursor
__global__ void scan3_kernel(const int* __restrict__ counts, int n, const int* __restrict__ bsum,
                             int* __restrict__ offsets, int* __restrict__ cursor, int total) {
  int i = blockIdx.x * 256 + threadIdx.x;
  int v = (i < n) ? counts[i] : 0;
  int lane = threadIdx.x & 63, w = threadIdx.x >> 6;
  int incl = v;
  for (int d = 1; d < 64; d <<= 1) { int u = __shfl_up(incl, d, 64); if (lane >= d) incl += u; }
  __shared__ int wsum[4];
  if (lane == 63) wsum[w] = incl;
  __syncthreads();
  int pre = bsum[blockIdx.x];
  for (int j = 0; j < w; ++j) pre += wsum[j];
  if (i < n) {
    int excl = pre + incl - v;
    offsets[i] = excl;
    cursor[i] = excl;
  }
  if (i == 0) offsets[n] = total;
}

__global__ void fill_kernel(const int* __restrict__ ei, const float* __restrict__ pseudo,
                            int E, int* __restrict__ cursor, int* __restrict__ src_s,
                            float2* __restrict__ ps_s) {
  int e = blockIdx.x * blockDim.x + threadIdx.x;
  if (e >= E) return;
  int d = ei[E + e];
  int s = ei[e];
  int p = atomicAdd(&cursor[d], 1);
  src_s[p] = s;
  ps_s[p] = ((const float2*)pseudo)[e];
}

// -------- weight repack, TRANSPOSED: Wt[64 cols][640 k]; k 0..575 = W.flat, 576..639 = root

__global__ void wconv_kernel(const float* __restrict__ W, const float* __restrict__ root,
                             unsigned short* __restrict__ Wt) {
  int i = blockIdx.x * blockDim.x + threadIdx.x;
  if (i >= 640 * 64) return;
  int co = i / 640, r = i % 640;
  float v = (r < 576) ? W[r * 64 + co] : root[(r - 576) * 64 + co];
  Wt[i] = f2bf(v);
}

// -------- x -> bf16 (halves layer-1 gather traffic)

__global__ void xconv_kernel(const float4* __restrict__ x4, ushort4* __restrict__ xh4, int n4) {
  int i = blockIdx.x * blockDim.x + threadIdx.x;
  if (i < n4) {
    float4 v = x4[i];
    ushort4 o;
    o.x = f2bf(v.x); o.y = f2bf(v.y); o.z = f2bf(v.z); o.w = f2bf(v.w);
    xh4[i] = o;
  }
}

// ---------------- per-node aggregation: one wave per node, lane = channel ----------------

__global__ void agg_kernel(const int* __restrict__ offsets, const int* __restrict__ src_s,
                           const float2* __restrict__ ps_s, const unsigned short* __restrict__ Xh,
                           unsigned short* __restrict__ A, int node0, int nodeEnd) {
  int wid = (blockIdx.x * blockDim.x + threadIdx.x) >> 6;
  int lane = threadIdx.x & 63;
  int n = node0 + wid;
  if (n >= nodeEnd) return;
  float acc[9];
#pragma unroll
  for (int k = 0; k < 9; ++k) acc[k] = 0.f;
  int beg = offsets[n], end = offsets[n + 1];
  int s_pf = 0; float2 uv_pf = make_float2(0.f, 0.f);
  if (beg < end) { s_pf = src_s[beg]; uv_pf = ps_s[beg]; }
  for (int j = beg; j < end; ++j) {
    int s = s_pf; float2 uv = uv_pf;
    if (j + 1 < end) { s_pf = src_s[j + 1]; uv_pf = ps_s[j + 1]; }  // software prefetch
    float xv = bf2f(Xh[(size_t)s * 64 + lane]);
    float u = uv.x, v = uv.y;
    float b0 = 0.5f * u * u - u + 0.5f, b1 = -u * u + u + 0.5f, b2 = 0.5f * u * u;
    float c0 = 0.5f * v * v - v + 0.5f, c1 = -v * v + v + 0.5f, c2 = 0.5f * v * v;
    float t0 = b0 * xv, t1 = b1 * xv, t2 = b2 * xv;
    acc[0] += t0 * c0; acc[1] += t0 * c1; acc[2] += t0 * c2;
    acc[3] += t1 * c0; acc[4] += t1 * c1; acc[5] += t1 * c2;
    acc[6] += t2 * c0; acc[7] += t2 * c1; acc[8] += t2 * c2;
  }
  float self = bf2f(Xh[(size_t)n * 64 + lane]);
  size_t row = (size_t)(n - node0) * 640;
#pragma unroll
  for (int k = 0; k < 9; ++k) A[row + k * 64 + lane] = f2bf(acc[k]);
  A[row + 576 + lane] = f2bf(self);
}

// ---------------- MFMA GEMM: [M,640](bf16) @ Wt^T + bias, relu ----------------

template <bool OUTBF16>
__global__ __launch_bounds__(256) void gemm_kernel(const unsigned short* __restrict__ A,
                                                   const unsigned short* __restrict__ Wt,
                                                   const float* __restrict__ bias,
                                                   void* __restrict__ outv, int M, int node0) {
  int tid = threadIdx.x;
  int w = tid >> 6, lane = tid & 63;
  int rowBase = blockIdx.x * 64 + w * 16;
  int rA = rowBase + (lane & 15);
  int kg = lane >> 4;
  const bool rowOK = rA < M;
  f32x4 acc[4] = {{0.f, 0.f, 0.f, 0.f}, {0.f, 0.f, 0.f, 0.f},
                  {0.f, 0.f, 0.f, 0.f}, {0.f, 0.f, 0.f, 0.f}};
#pragma unroll
  for (int kk = 0; kk < 20; ++kk) {
    int kbase = kk * 32 + kg * 8;
    bf16x8 af = {0, 0, 0, 0, 0, 0, 0, 0};
    if (rowOK) af = *(const bf16x8*)(A + (size_t)rA * 640 + kbase);
#pragma unroll
    for (int t = 0; t < 4; ++t) {
      bf16x8 bfr = *(const bf16x8*)(Wt + (size_t)(t * 16 + (lane & 15)) * 640 + kbase);
      acc[t] = __builtin_amdgcn_mfma_f32_16x16x32_bf16(af, bfr, acc[t], 0, 0, 0);
    }
  }
  int rowE0 = rowBase + (lane >> 4) * 4;  // C/D: col = lane&15, row = (lane>>4)*4 + reg
#pragma unroll
  for (int t = 0; t < 4; ++t) {
    int col = t * 16 + (lane & 15);
    float bv = bias[col];
#pragma unroll
    for (int r = 0; r < 4; ++r) {
      int row = rowE0 + r;
      if (row < M) {
        float val = fmaxf(acc[t][r] + bv, 0.f);
        size_t idx = (size_t)(node0 + row) * 64 + col;
        if (OUTBF16) ((unsigned short*)outv)[idx] = f2bf(val);
        else ((float*)outv)[idx] = val;
      }
    }
  }
}

// ---------------- host ----------------

extern "C" void kernel_launch(void* const* d_in, const int* in_sizes, int n_in,
                              void* d_out, int out_size, void* d_ws, size_t ws_size,
                              hipStream_t stream) {
  const float* x = (const float*)d_in[0];
  const int* ei = (const int*)d_in[1];
  const float* pseudo = (const float*)d_in[2];
  const float* W1 = (const float*)d_in[3];
  const float* root1 = (const float*)d_in[4];
  const float* b1 = (const float*)d_in[5];
  const float* W2 = (const float*)d_in[6];
  const float* root2 = (const float*)d_in[7];
  const float* b2 = (const float*)d_in[8];

  const int N = in_sizes[0] / 64;
  const int E = in_sizes[1] / 2;
  const int G = (N + 255) / 256;

  char* p = (char*)d_ws;
  auto carve = [&](size_t bytes) -> void* {
    void* r = (void*)p;
    p += (bytes + 255) & ~(size_t)255;
    return r;
  };
  int* counts = (int*)carve((size_t)N * 4);
  int* offsets = (int*)carve((size_t)(N + 1) * 4);
  int* cursor = (int*)carve((size_t)N * 4);
  int* bsum = (int*)carve((size_t)G * 4);
  int* src_s = (int*)carve((size_t)E * 4);
  float2* ps_s = (float2*)carve((size_t)E * 8);
  unsigned short* Wt1 = (unsigned short*)carve(640 * 64 * 2);
  unsigned short* Wt2 = (unsigned short*)carve(640 * 64 * 2);
  unsigned short* h = (unsigned short*)carve((size_t)N * 64 * 2);
  unsigned short* xh = (unsigned short*)carve((size_t)N * 64 * 2);
  size_t used = (size_t)(p - (char*)d_ws);
  size_t avail = ws_size > used ? ws_size - used : 0;
  long long crMax = (long long)(avail / (640 * 2));
  int CR;
  if (crMax >= (long long)N) CR = N;
  else {
    CR = (int)crMax & ~63;
    if (CR < 64) CR = 64;
  }
  unsigned short* Agg = (unsigned short*)p;

  hipMemsetAsync(counts, 0, (size_t)N * 4, stream);
  count_kernel<<<(E + 255) / 256, 256, 0, stream>>>(ei, E, counts);
  scan1_kernel<<<G, 256, 0, stream>>>(counts, N, bsum);
  scan2_kernel<<<1, 512, 0, stream>>>(bsum, G);
  scan3_kernel<<<G, 256, 0, stream>>>(counts, N, bsum, offsets, cursor, E);
  fill_kernel<<<(E + 255) / 256, 256, 0, stream>>>(ei, pseudo, E, cursor, src_s, ps_s);
  wconv_kernel<<<160, 256, 0, stream>>>(W1, root1, Wt1);
  wconv_kernel<<<160, 256, 0, stream>>>(W2, root2, Wt2);
  xconv_kernel<<<(N * 16 + 255) / 256, 256, 0, stream>>>((const float4*)x, (ushort4*)xh, N * 16);

  // layer 1: X = xh (bf16) -> h (bf16)
  for (int n0 = 0; n0 < N; n0 += CR) {
    int ncur = min(CR, N - n0);
    agg_kernel<<<(ncur + 3) / 4, 256, 0, stream>>>(offsets, src_s, ps_s, xh, Agg, n0, n0 + ncur);
    gemm_kernel<true><<<(ncur + 63) / 64, 256, 0, stream>>>(Agg, Wt1, b1, (void*)h, ncur, n0);
  }
  // layer 2: X = h (bf16) -> d_out (fp32)
  for (int n0 = 0; n0 < N; n0 += CR) {
    int ncur = min(CR, N - n0);
    agg_kernel<<<(ncur + 3) / 4, 256, 0, stream>>>(offsets, src_s, ps_s, h, Agg, n0, n0 + ncur);
    gemm_kernel<false><<<(ncur + 63) / 64, 256, 0, stream>>>(Agg, Wt2, b2, d_out, ncur, n0);
  }
}